// Round 7
// baseline (426.734 us; speedup 1.0000x reference)
//
#include <hip/hip_runtime.h>

typedef _Float16 f16;
typedef __attribute__((ext_vector_type(4))) _Float16 f16x4;
typedef __attribute__((ext_vector_type(8))) _Float16 f16x8;
typedef __attribute__((ext_vector_type(4))) float f32x4;
typedef __attribute__((ext_vector_type(4))) int i32x4;

#define B_ 8192
#define D_ 784
#define H_ 1024
#define L_ 128
#define T_ 10
#define KP1 1024         // D padded to 1024 (uniform K for big layers)
#define NPH 1024         // head N padded to 1024
#define MAXTILES (B_/128 + T_)   // 74  (128-row map, for enc3 kernel)
#define MAXT256 (B_/256 + T_)    // 42  (256-row map)
#define PADROWS 256
#define CBUF 65536       // 64KB per LDS buffer: A [256][64] 32KB + B [256][64] 32KB

// ctrl int indices
#define C_COUNT 0
#define C_CURS 16
#define C_OFFS 32
#define C_NTILES 49
#define C_NTILES2 50
#define C_TTASK 64
#define C_TROW 160
#define C_TTASK2 256
#define C_TROW2 320

__global__ void k_init(int* ctrl) {
    if (threadIdx.x < 64) ctrl[threadIdx.x] = 0;
}

__global__ void k_count(const int* __restrict__ task, int* __restrict__ ctrl) {
    int b = blockIdx.x * 256 + threadIdx.x;
    if (b < B_) atomicAdd(&ctrl[C_COUNT + task[b]], 1);
}

__global__ void k_scan(int* ctrl) {
    if (threadIdx.x == 0 && blockIdx.x == 0) {
        int off = 0;
        ctrl[C_OFFS] = 0;
        for (int t = 0; t < T_; ++t) { off += ctrl[C_COUNT + t]; ctrl[C_OFFS + t + 1] = off; }
        int nt = 0;
        for (int t = 0; t < T_; ++t)
            for (int r = ctrl[C_OFFS + t]; r < ctrl[C_OFFS + t + 1]; r += 128) {
                ctrl[C_TTASK + nt] = t; ctrl[C_TROW + nt] = r; ++nt;
            }
        ctrl[C_NTILES] = nt;
        int nt2 = 0;
        for (int t = 0; t < T_; ++t)
            for (int r = ctrl[C_OFFS + t]; r < ctrl[C_OFFS + t + 1]; r += 256) {
                ctrl[C_TTASK2 + nt2] = t; ctrl[C_TROW2 + nt2] = r; ++nt2;
            }
        ctrl[C_NTILES2] = nt2;
    }
}

__global__ void k_scatter(const int* __restrict__ task, int* __restrict__ ctrl, int* __restrict__ perm) {
    int b = blockIdx.x * 256 + threadIdx.x;
    if (b >= B_) return;
    int t = task[b];
    int i = ctrl[C_OFFS + t] + atomicAdd(&ctrl[C_CURS + t], 1);
    perm[i] = b;
}

__global__ void k_gather_x(const float* __restrict__ x, const int* __restrict__ perm, f16* __restrict__ Xp) {
    int i = blockIdx.x;
    int r = perm[i];
    int c = threadIdx.x * 4;
    if (c >= KP1) return;
    f16x4 o = (f16x4){0, 0, 0, 0};
    if (c < D_) {
        float4 v = *(const float4*)(x + (long)r * D_ + c);
        o[0] = (f16)v.x; o[1] = (f16)v.y; o[2] = (f16)v.z; o[3] = (f16)v.w;
    }
    *(f16x4*)(Xp + (long)i * KP1 + c) = o;
}

// transpose-convert: src fp32 [T][K][N] -> dst f16 [T][Np][Kp], zero-padded.
__global__ void k_convW(const float* __restrict__ src, f16* __restrict__ dst,
                        int K, int N, int Kp, int Np) {
    __shared__ float tile[64][65];
    int k0 = blockIdx.x * 64, n0 = blockIdx.y * 64, t = blockIdx.z;
    const float* s = src + (long)t * K * N;
    f16* d = dst + (long)t * Np * Kp;
    int tid = threadIdx.x;
    int r = tid >> 2;
    int cb = (tid & 3) * 16;
    int gk = k0 + r;
#pragma unroll
    for (int j = 0; j < 4; ++j) {
        int gn = n0 + cb + j * 4;
        float4 v = {0.f, 0.f, 0.f, 0.f};
        if (gk < K) {
            const float* p = s + (long)gk * N + gn;
            if (gn + 3 < N) v = *(const float4*)p;
            else {
                if (gn + 0 < N) v.x = p[0];
                if (gn + 1 < N) v.y = p[1];
                if (gn + 2 < N) v.z = p[2];
                if (gn + 3 < N) v.w = p[3];
            }
        }
        tile[r][cb + j * 4 + 0] = v.x;
        tile[r][cb + j * 4 + 1] = v.y;
        tile[r][cb + j * 4 + 2] = v.z;
        tile[r][cb + j * 4 + 3] = v.w;
    }
    __syncthreads();
    int n = n0 + r;
#pragma unroll
    for (int j = 0; j < 2; ++j) {
        int kk = cb + j * 8;
        f16x8 o;
#pragma unroll
        for (int u = 0; u < 8; ++u) o[u] = (f16)tile[kk + u][r];
        if (n < Np) *(f16x8*)(d + (long)n * Kp + k0 + kk) = o;
    }
}

// z = mu + exp(ls) * eps  (permuted rows)
__global__ void k_z(const float* __restrict__ mu, const float* __restrict__ ls,
                    const float* __restrict__ eps, const int* __restrict__ perm,
                    f16* __restrict__ Z) {
    long gid = (long)blockIdx.x * 256 + threadIdx.x;
    int i = (int)(gid >> 7), c = (int)(gid & 127);
    int r = perm[i];
    float m = mu[(long)r * L_ + c];
    float l = ls[(long)r * L_ + c];
    Z[(long)i * L_ + c] = (f16)(m + __expf(l) * eps[(long)r * L_ + c]);
}

#define DSR(dst, addr, IMM) \
    asm volatile("ds_read_b128 %0, %1 offset:" #IMM : "=v"(dst) : "v"(addr))

// ---------------------------------------------------------------------------
// 256x256 tile, BK=64, double-buffered, stage-1-ahead (drain at iter end).
// 8 waves = 2M x 4N; per-wave 128x64 = acc[8][4] frags of 16x16 (f16 K=32).
// LDS buffer (64KB): A [256 rows][64 k] at 0; B [256 nrows][64 k] at 32768.
// Row = 128B = 8 slots of 16B; slot XOR-swizzled with (row&7), both sides.
// Staging per K-tile: 8 global_load_lds calls (A:4 + B:4, 8KB each).
// Per iter: 24 ds_read_b128, 64 MFMA (lgkmcnt(12) split over 2 k-steps).
// ---------------------------------------------------------------------------
template <int EPI, bool GROUPED>
__global__ __launch_bounds__(512, 2)
void k_gemmC(const f16* __restrict__ A,
             const f16* __restrict__ W, long wstride,
             const float* __restrict__ bias, int bstride,
             int K, int N, int ntn,
             f16* __restrict__ outF16, float* __restrict__ o0,
             const int* __restrict__ ctrl, const int* __restrict__ perm) {
    extern __shared__ char lds[];
    int tid = threadIdx.x, lane = tid & 63;
    int wave = tid >> 6, wm = wave >> 2, wn = wave & 3;

    // T1: bijective XCD swizzle (m204)
    int nwg = gridDim.x, orig = blockIdx.x;
    int qq = nwg >> 3, rr8 = nwg & 7, xcd = orig & 7, idx = orig >> 3;
    int wgid = (xcd < rr8 ? xcd * (qq + 1) : rr8 * (qq + 1) + (xcd - rr8) * qq) + idx;
    int tm = wgid / ntn, tn = wgid - tm * ntn;

    int t, row0, mrows;
    if (GROUPED) {
        if (tm >= ctrl[C_NTILES2]) return;
        t = ctrl[C_TTASK2 + tm];
        row0 = ctrl[C_TROW2 + tm];
        mrows = min(256, ctrl[C_OFFS + t + 1] - row0);
    } else {
        t = 0; row0 = tm * 256; mrows = 256;
    }
    const f16* Wt = W + (long)t * wstride;
    const float* bt = bias + (long)t * bstride;
    int n0 = tn * 256;

    // staging: thread g covers (row g>>3 of a 64-row chunk, LDS slot g&7);
    // global 16B-chunk index = (g&7) ^ (row&7) (inverse swizzle).
    int rowc = tid >> 3;
    long srcElem = (long)rowc * K + (((tid & 7) ^ (rowc & 7)) << 3);
    int dstOff = wave << 10;   // wave-uniform; HW adds lane*16
    const f16* Abase = A + (long)row0 * K + srcElem;
    const f16* Bbase = Wt + (long)n0 * K + srcElem;

    f32x4 acc[8][4];
#pragma unroll
    for (int i = 0; i < 8; ++i)
#pragma unroll
        for (int j = 0; j < 4; ++j) acc[i][j] = (f32x4){0.f, 0.f, 0.f, 0.f};

    auto STAGE = [&](int buf, int kt) {
        const f16* a = Abase + kt * 64;
        const f16* b = Bbase + kt * 64;
        char* base = lds + buf * CBUF;
#pragma unroll
        for (int c = 0; c < 4; ++c)
            __builtin_amdgcn_global_load_lds(
                (const __attribute__((address_space(1))) unsigned int*)(a + (long)c * 64 * K),
                (__attribute__((address_space(3))) unsigned int*)(base + c * 8192 + dstOff), 16, 0, 0);
#pragma unroll
        for (int c = 0; c < 4; ++c)
            __builtin_amdgcn_global_load_lds(
                (const __attribute__((address_space(1))) unsigned int*)(b + (long)c * 64 * K),
                (__attribute__((address_space(3))) unsigned int*)(base + 32768 + c * 8192 + dstOff), 16, 0, 0);
    };

    // read addressing: slot = ((ks<<2)|(lane>>4)) ^ (lane&7); ks=1 addr = ks0 ^ 64.
    int slot0 = ((lane >> 4) ^ (lane & 7)) << 4;
    int aoffB = (wm * 128 + (lane & 15)) * 128 + slot0;           // + mi*2048 imm
    int boffB = 32768 + (wn * 64 + (lane & 15)) * 128 + slot0;    // + nj*2048 imm

    int NI = K >> 6;
    STAGE(0, 0);
    asm volatile("s_waitcnt vmcnt(0)" ::: "memory");
    asm volatile("s_barrier" ::: "memory");

    for (int i = 0; i < NI; ++i) {
        if (i + 1 < NI) STAGE((i + 1) & 1, i + 1);   // full iter to land

        int base = (i & 1) * CBUF;
        int a0 = base + aoffB, b0 = base + boffB;
        int a1 = a0 ^ 64, b1 = b0 ^ 64;
        i32x4 ra0[8], rb0[4], ra1[8], rb1[4];
        DSR(ra0[0], a0, 0);     DSR(ra0[1], a0, 2048);
        DSR(ra0[2], a0, 4096);  DSR(ra0[3], a0, 6144);
        DSR(ra0[4], a0, 8192);  DSR(ra0[5], a0, 10240);
        DSR(ra0[6], a0, 12288); DSR(ra0[7], a0, 14336);
        DSR(rb0[0], b0, 0);     DSR(rb0[1], b0, 2048);
        DSR(rb0[2], b0, 4096);  DSR(rb0[3], b0, 6144);
        DSR(ra1[0], a1, 0);     DSR(ra1[1], a1, 2048);
        DSR(ra1[2], a1, 4096);  DSR(ra1[3], a1, 6144);
        DSR(ra1[4], a1, 8192);  DSR(ra1[5], a1, 10240);
        DSR(ra1[6], a1, 12288); DSR(ra1[7], a1, 14336);
        DSR(rb1[0], b1, 0);     DSR(rb1[1], b1, 2048);
        DSR(rb1[2], b1, 4096);  DSR(rb1[3], b1, 6144);

        asm volatile("s_waitcnt lgkmcnt(12)" ::: "memory");   // k-step 0 reads done
        __builtin_amdgcn_sched_barrier(0);
        __builtin_amdgcn_s_setprio(1);
#pragma unroll
        for (int mi = 0; mi < 8; ++mi)
#pragma unroll
            for (int nj = 0; nj < 4; ++nj)
                acc[mi][nj] = __builtin_amdgcn_mfma_f32_16x16x32_f16(
                    __builtin_bit_cast(f16x8, ra0[mi]), __builtin_bit_cast(f16x8, rb0[nj]),
                    acc[mi][nj], 0, 0, 0);
        __builtin_amdgcn_s_setprio(0);

        asm volatile("s_waitcnt lgkmcnt(0)" ::: "memory");
        __builtin_amdgcn_sched_barrier(0);
        __builtin_amdgcn_s_setprio(1);
#pragma unroll
        for (int mi = 0; mi < 8; ++mi)
#pragma unroll
            for (int nj = 0; nj < 4; ++nj)
                acc[mi][nj] = __builtin_amdgcn_mfma_f32_16x16x32_f16(
                    __builtin_bit_cast(f16x8, ra1[mi]), __builtin_bit_cast(f16x8, rb1[nj]),
                    acc[mi][nj], 0, 0, 0);
        __builtin_amdgcn_s_setprio(0);

        if (i + 1 < NI) {
            asm volatile("s_waitcnt vmcnt(0)" ::: "memory");  // next tile landed
            asm volatile("s_barrier" ::: "memory");
        }
    }

    // epilogue
    int cq = lane >> 4, cr = lane & 15;
    float bv[4];
#pragma unroll
    for (int nj = 0; nj < 4; ++nj) {
        int gcol = n0 + wn * 64 + nj * 16 + cr;
        bv[nj] = (gcol < N) ? bt[gcol] : 0.f;
    }
#pragma unroll
    for (int mi = 0; mi < 8; ++mi) {
#pragma unroll
        for (int nj = 0; nj < 4; ++nj) {
#pragma unroll
            for (int reg = 0; reg < 4; ++reg) {
                int rl = wm * 128 + mi * 16 + cq * 4 + reg;
                if (rl >= mrows) continue;
                int gcol = n0 + wn * 64 + nj * 16 + cr;
                if (gcol >= N) continue;
                float v = acc[mi][nj][reg] + bv[nj];
                int grow = row0 + rl;
                if (EPI == 0) {
                    outF16[(long)grow * H_ + gcol] = (f16)(v > 0.f ? v : 0.f);
                } else {
                    o0[(long)perm[grow] * D_ + gcol] = 1.f / (1.f + __expf(-v));
                }
            }
        }
    }
}

// 128x128 2-phase kernel (enc3 only: N=256, EPI 1 mu/ls scatter).
template <int EPI, bool GROUPED>
__global__ __launch_bounds__(256)
void k_gemm(const f16* __restrict__ A,
            const f16* __restrict__ W, long wstride,
            const float* __restrict__ bias, int bstride,
            int K, int N,
            f16* __restrict__ outF16,
            float* __restrict__ o0, float* __restrict__ o1,
            const int* __restrict__ ctrl, const int* __restrict__ perm) {
    __shared__ f16 sA[2 * 8192];
    __shared__ f16 sB[2 * 8192];
    int tid = threadIdx.x;
    int lane = tid & 63, wave = tid >> 6;
    int wm = wave >> 1, wn = wave & 1;
    int n0 = blockIdx.x * 128;

    int t, row0, mrows;
    if (GROUPED) {
        int nt = ctrl[C_NTILES];
        if ((int)blockIdx.y >= nt) return;
        t = ctrl[C_TTASK + blockIdx.y];
        row0 = ctrl[C_TROW + blockIdx.y];
        mrows = min(128, ctrl[C_OFFS + t + 1] - row0);
    } else {
        t = 0; row0 = blockIdx.y * 128; mrows = 128;
    }
    const f16* Wt = W + (long)t * wstride;
    const float* bt = bias + (long)t * bstride;

    int srow = tid >> 3, scol = (tid & 7) << 3;

    f32x4 acc[4][4];
#pragma unroll
    for (int i = 0; i < 4; ++i)
#pragma unroll
        for (int j = 0; j < 4; ++j) acc[i][j] = (f32x4){0.f, 0.f, 0.f, 0.f};

    auto stage = [&](int buf, int kt) {
        int k0 = kt << 6;
        const f16* Ab = A + (long)row0 * K + k0;
        const f16* Bb = Wt + (long)n0 * K + k0;
#pragma unroll
        for (int rr = 0; rr < 4; ++rr) {
            __builtin_amdgcn_global_load_lds(
                (const __attribute__((address_space(1))) unsigned int*)(Ab + (long)(srow + 32 * rr) * K + scol),
                (__attribute__((address_space(3))) unsigned int*)(sA + buf * 8192 + rr * 2048 + wave * 512),
                16, 0, 0);
            __builtin_amdgcn_global_load_lds(
                (const __attribute__((address_space(1))) unsigned int*)(Bb + (long)(srow + 32 * rr) * K + scol),
                (__attribute__((address_space(3))) unsigned int*)(sB + buf * 8192 + rr * 2048 + wave * 512),
                16, 0, 0);
        }
    };

    auto compute = [&](int buf) {
        const f16* bA = sA + buf * 8192;
        const f16* bB = sB + buf * 8192;
#pragma unroll
        for (int kk = 0; kk < 2; ++kk) {
            f16x8 af[4], bf[4];
            int ko = kk * 32 + ((lane >> 4) << 3);
#pragma unroll
            for (int mi = 0; mi < 4; ++mi)
                af[mi] = *(const f16x8*)(bA + (wm * 64 + mi * 16 + (lane & 15)) * 64 + ko);
#pragma unroll
            for (int nj = 0; nj < 4; ++nj)
                bf[nj] = *(const f16x8*)(bB + (wn * 64 + nj * 16 + (lane & 15)) * 64 + ko);
#pragma unroll
            for (int mi = 0; mi < 4; ++mi)
#pragma unroll
                for (int nj = 0; nj < 4; ++nj)
                    acc[mi][nj] = __builtin_amdgcn_mfma_f32_16x16x32_f16(af[mi], bf[nj], acc[mi][nj], 0, 0, 0);
        }
    };

    int nk = K >> 6;
    stage(0, 0);
    __syncthreads();
    int cur = 0;
    for (int kt = 0; kt + 1 < nk; ++kt) {
        stage(cur ^ 1, kt + 1);
        compute(cur);
        __syncthreads();
        cur ^= 1;
    }
    compute(cur);

    int cq = lane >> 4;
    int cr = lane & 15;
#pragma unroll
    for (int mi = 0; mi < 4; ++mi) {
#pragma unroll
        for (int nj = 0; nj < 4; ++nj) {
#pragma unroll
            for (int reg = 0; reg < 4; ++reg) {
                int rl = wm * 64 + mi * 16 + cq * 4 + reg;
                int cl = wn * 64 + nj * 16 + cr;
                if (rl >= mrows) continue;
                int gcol = n0 + cl;
                if (gcol >= N) continue;
                float v = acc[mi][nj][reg] + bt[gcol];
                int grow = row0 + rl;
                if (EPI == 0) {
                    outF16[(long)grow * H_ + gcol] = (f16)(v > 0.f ? v : 0.f);
                } else if (EPI == 1) {
                    int r = perm[grow];
                    if (gcol < L_) o0[(long)r * L_ + gcol] = v;
                    else o1[(long)r * L_ + (gcol - L_)] = v;
                } else {
                    int r = perm[grow];
                    o0[(long)r * D_ + gcol] = 1.f / (1.f + __expf(-v));
                }
            }
        }
    }
}

extern "C" void kernel_launch(void* const* d_in, const int* in_sizes, int n_in,
                              void* d_out, int out_size, void* d_ws, size_t ws_size,
                              hipStream_t stream) {
    const float* x   = (const float*)d_in[0];
    const float* eps = (const float*)d_in[1];
    const float* eW1 = (const float*)d_in[2];
    const float* eb1 = (const float*)d_in[3];
    const float* eW2 = (const float*)d_in[4];
    const float* eb2 = (const float*)d_in[5];
    const float* eW3 = (const float*)d_in[6];
    const float* eb3 = (const float*)d_in[7];
    const float* dW1 = (const float*)d_in[8];
    const float* db1 = (const float*)d_in[9];
    const float* dW2 = (const float*)d_in[10];
    const float* db2 = (const float*)d_in[11];
    const float* hW  = (const float*)d_in[12];
    const float* hb  = (const float*)d_in[13];
    const int* task  = (const int*)d_in[14];

    float* out = (float*)d_out;
    float* recon = out;
    float* mu = out + (size_t)B_ * D_;
    float* ls = mu + (size_t)B_ * L_;

    char* w = (char*)d_ws;
    size_t o = 0;
    auto alloc = [&](size_t bytes) -> char* {
        char* p = w + o;
        o = (o + bytes + 255) & ~(size_t)255;
        return p;
    };
    int* ctrl  = (int*)alloc(4096);
    int* perm  = (int*)alloc((size_t)B_ * 4);
    f16* Xp    = (f16*)alloc((size_t)(B_ + PADROWS) * KP1 * 2);
    f16* H1    = (f16*)alloc((size_t)(B_ + PADROWS) * H_ * 2);
    f16* H2    = (f16*)alloc((size_t)(B_ + PADROWS) * H_ * 2);
    f16* Z     = (f16*)alloc((size_t)(B_ + PADROWS) * L_ * 2);
    f16* Wt1   = (f16*)alloc((size_t)T_ * H_ * KP1 * 2);
    f16* Wt2   = (f16*)alloc((size_t)T_ * H_ * H_ * 2);
    f16* Wt3   = (f16*)alloc((size_t)T_ * 256 * H_ * 2);
    f16* WtD1  = (f16*)alloc((size_t)H_ * L_ * 2);
    f16* WtD2  = (f16*)alloc((size_t)H_ * H_ * 2);
    f16* WtH   = (f16*)alloc((size_t)T_ * NPH * H_ * 2);
    if (o > ws_size) return;

    (void)hipFuncSetAttribute((const void*)&k_gemmC<0, true>,  hipFuncAttributeMaxDynamicSharedMemorySize, 2 * CBUF);
    (void)hipFuncSetAttribute((const void*)&k_gemmC<0, false>, hipFuncAttributeMaxDynamicSharedMemorySize, 2 * CBUF);
    (void)hipFuncSetAttribute((const void*)&k_gemmC<2, true>,  hipFuncAttributeMaxDynamicSharedMemorySize, 2 * CBUF);

    k_init<<<1, 64, 0, stream>>>(ctrl);
    k_count<<<B_ / 256, 256, 0, stream>>>(task, ctrl);
    k_scan<<<1, 1, 0, stream>>>(ctrl);
    k_scatter<<<B_ / 256, 256, 0, stream>>>(task, ctrl, perm);
    k_gather_x<<<B_, 256, 0, stream>>>(x, perm, Xp);

    k_convW<<<dim3(KP1 / 64, H_ / 64, T_), 256, 0, stream>>>(eW1, Wt1, D_, H_, KP1, H_);
    k_convW<<<dim3(H_ / 64, H_ / 64, T_), 256, 0, stream>>>(eW2, Wt2, H_, H_, H_, H_);
    k_convW<<<dim3(H_ / 64, 256 / 64, T_), 256, 0, stream>>>(eW3, Wt3, H_, 256, H_, 256);
    k_convW<<<dim3(L_ / 64, H_ / 64, 1), 256, 0, stream>>>(dW1, WtD1, L_, H_, L_, H_);
    k_convW<<<dim3(H_ / 64, H_ / 64, 1), 256, 0, stream>>>(dW2, WtD2, H_, H_, H_, H_);
    k_convW<<<dim3(H_ / 64, NPH / 64, T_), 256, 0, stream>>>(hW, WtH, H_, D_, H_, NPH);

    int gridG = MAXT256 * 4;       // 168 (grouped, 4 N-tiles of 256)
    int gridD = (B_ / 256) * 4;    // 128 (dense)

    // encoder layer 1: Xp(K=1024) @ Wt1 -> relu -> H1
    k_gemmC<0, true><<<gridG, 512, 2 * CBUF, stream>>>(
        Xp, Wt1, (long)H_ * KP1, eb1, H_, KP1, H_, 4, H1, nullptr, ctrl, perm);
    // encoder layer 2: H1 @ Wt2 -> relu -> H2
    k_gemmC<0, true><<<gridG, 512, 2 * CBUF, stream>>>(
        H1, Wt2, (long)H_ * H_, eb2, H_, H_, H_, 4, H2, nullptr, ctrl, perm);
    // encoder layer 3 (N=256): 128^2 kernel, mu/ls scatter
    k_gemm<1, true><<<dim3(256 / 128, MAXTILES), 256, 0, stream>>>(
        H2, Wt3, (long)256 * H_, eb3, 256, H_, 256, nullptr, mu, ls, ctrl, perm);
    // z = mu + exp(ls)*eps
    k_z<<<(B_ * L_) / 256, 256, 0, stream>>>(mu, ls, eps, perm, Z);
    // decoder layer 1: Z(K=128) @ WtD1 -> relu -> H1
    k_gemmC<0, false><<<gridD, 512, 2 * CBUF, stream>>>(
        Z, WtD1, 0, db1, 0, L_, H_, 4, H1, nullptr, ctrl, perm);
    // decoder layer 2: H1 @ WtD2 -> relu -> H2
    k_gemmC<0, false><<<gridD, 512, 2 * CBUF, stream>>>(
        H1, WtD2, 0, db2, 0, H_, H_, 4, H2, nullptr, ctrl, perm);
    // head: H2 @ WtH -> sigmoid -> recon (scatter fp32)
    k_gemmC<2, true><<<gridG, 512, 2 * CBUF, stream>>>(
        H2, WtH, (long)NPH * H_, hb, D_, H_, D_, 4, nullptr, recon, ctrl, perm);
}

// Round 8
// 333.095 us; speedup vs baseline: 1.2811x; 1.2811x over previous
//
#include <hip/hip_runtime.h>

typedef _Float16 f16;
typedef __attribute__((ext_vector_type(4))) _Float16 f16x4;
typedef __attribute__((ext_vector_type(8))) _Float16 f16x8;
typedef __attribute__((ext_vector_type(4))) float f32x4;

#define B_ 8192
#define D_ 784
#define H_ 1024
#define L_ 128
#define T_ 10
#define KP1 896          // D padded to multiple of 64
#define NPH 896          // head N padded to 896 (7 x 128 tiles)
#define MAXTILES (B_/128 + T_)   // 74 (128-row tile map)
#define PADROWS 256

// ctrl int indices
#define C_COUNT 0
#define C_CURS 16
#define C_OFFS 32
#define C_NTILES 49
#define C_TTASK 64
#define C_TROW 160

__global__ void k_init(int* ctrl) {
    if (threadIdx.x < 64) ctrl[threadIdx.x] = 0;
}

__global__ void k_count(const int* __restrict__ task, int* __restrict__ ctrl) {
    int b = blockIdx.x * 256 + threadIdx.x;
    if (b < B_) atomicAdd(&ctrl[C_COUNT + task[b]], 1);
}

__global__ void k_scan(int* ctrl) {
    if (threadIdx.x == 0 && blockIdx.x == 0) {
        int off = 0;
        ctrl[C_OFFS] = 0;
        for (int t = 0; t < T_; ++t) { off += ctrl[C_COUNT + t]; ctrl[C_OFFS + t + 1] = off; }
        int nt = 0;
        for (int t = 0; t < T_; ++t)
            for (int r = ctrl[C_OFFS + t]; r < ctrl[C_OFFS + t + 1]; r += 128) {
                ctrl[C_TTASK + nt] = t; ctrl[C_TROW + nt] = r; ++nt;
            }
        ctrl[C_NTILES] = nt;
    }
}

__global__ void k_scatter(const int* __restrict__ task, int* __restrict__ ctrl, int* __restrict__ perm) {
    int b = blockIdx.x * 256 + threadIdx.x;
    if (b >= B_) return;
    int t = task[b];
    int i = ctrl[C_OFFS + t] + atomicAdd(&ctrl[C_CURS + t], 1);
    perm[i] = b;
}

__global__ void k_gather_x(const float* __restrict__ x, const int* __restrict__ perm, f16* __restrict__ Xp) {
    int i = blockIdx.x;
    int r = perm[i];
    int c = threadIdx.x * 4;
    if (c >= KP1) return;
    f16x4 o = (f16x4){0, 0, 0, 0};
    if (c < D_) {
        float4 v = *(const float4*)(x + (long)r * D_ + c);
        o[0] = (f16)v.x; o[1] = (f16)v.y; o[2] = (f16)v.z; o[3] = (f16)v.w;
    }
    *(f16x4*)(Xp + (long)i * KP1 + c) = o;
}

// transpose-convert: src fp32 [T][K][N] -> dst f16 [T][Np][Kp], zero-padded.
__global__ void k_convW(const float* __restrict__ src, f16* __restrict__ dst,
                        int K, int N, int Kp, int Np) {
    __shared__ float tile[64][65];
    int k0 = blockIdx.x * 64, n0 = blockIdx.y * 64, t = blockIdx.z;
    const float* s = src + (long)t * K * N;
    f16* d = dst + (long)t * Np * Kp;
    int tid = threadIdx.x;
    int r = tid >> 2;
    int cb = (tid & 3) * 16;
    int gk = k0 + r;
#pragma unroll
    for (int j = 0; j < 4; ++j) {
        int gn = n0 + cb + j * 4;
        float4 v = {0.f, 0.f, 0.f, 0.f};
        if (gk < K) {
            const float* p = s + (long)gk * N + gn;
            if (gn + 3 < N) v = *(const float4*)p;
            else {
                if (gn + 0 < N) v.x = p[0];
                if (gn + 1 < N) v.y = p[1];
                if (gn + 2 < N) v.z = p[2];
                if (gn + 3 < N) v.w = p[3];
            }
        }
        tile[r][cb + j * 4 + 0] = v.x;
        tile[r][cb + j * 4 + 1] = v.y;
        tile[r][cb + j * 4 + 2] = v.z;
        tile[r][cb + j * 4 + 3] = v.w;
    }
    __syncthreads();
    int n = n0 + r;
#pragma unroll
    for (int j = 0; j < 2; ++j) {
        int kk = cb + j * 8;
        f16x8 o;
#pragma unroll
        for (int u = 0; u < 8; ++u) o[u] = (f16)tile[kk + u][r];
        if (n < Np) *(f16x8*)(d + (long)n * Kp + k0 + kk) = o;
    }
}

// z = mu + exp(ls) * eps  (permuted rows)
__global__ void k_z(const float* __restrict__ mu, const float* __restrict__ ls,
                    const float* __restrict__ eps, const int* __restrict__ perm,
                    f16* __restrict__ Z) {
    long gid = (long)blockIdx.x * 256 + threadIdx.x;
    int i = (int)(gid >> 7), c = (int)(gid & 127);
    int r = perm[i];
    float m = mu[(long)r * L_ + c];
    float l = ls[(long)r * L_ + c];
    Z[(long)i * L_ + c] = (f16)(m + __expf(l) * eps[(long)r * L_ + c]);
}

// ---------------------------------------------------------------------------
// m97-faithful 128x128 GEMM, BK=64, SINGLE 32KB LDS buffer, 4 waves (2Mx2N),
// per-wave 64x64 = acc[4][4] of 16x16x32 f16 MFMA.
// Loop: STAGE(kt) -> __syncthreads -> compute -> __syncthreads. No asm.
// Latency hiding comes from 3+ co-resident blocks/CU (m114), not intra-block
// pipelining (m99/m100: explicit dbuf adds nothing at this occupancy).
// LDS rows are 128B = 8 x 16B slots, XOR-swizzled by (row&7); staging uses
// the inverse-swizzled global source (rule 21), reads apply the same XOR.
// EPI 0: relu->f16 [row][H_]; 1: mu/ls perm-scatter fp32; 2: sigmoid scatter.
// ---------------------------------------------------------------------------
template <int EPI, bool GROUPED>
__global__ __launch_bounds__(256, 3)
void k_gemmD(const f16* __restrict__ A,
             const f16* __restrict__ W, long wstride,
             const float* __restrict__ bias, int bstride,
             int K, int N, int ntn,
             f16* __restrict__ outF16, float* __restrict__ o0, float* __restrict__ o1,
             const int* __restrict__ ctrl, const int* __restrict__ perm) {
    __shared__ char lds[32768];   // A [128][64]f16 @0 (16KB), B @16384 (16KB)
    int tid = threadIdx.x, lane = tid & 63;
    int wave = tid >> 6, wm = wave >> 1, wn = wave & 1;

    // bijective XCD swizzle (m204)
    int nwg = gridDim.x, orig = blockIdx.x;
    int qq = nwg >> 3, rr8 = nwg & 7, xcd = orig & 7, idx = orig >> 3;
    int wgid = (xcd < rr8 ? xcd * (qq + 1) : rr8 * (qq + 1) + (xcd - rr8) * qq) + idx;
    int tm = wgid / ntn, tn = wgid - tm * ntn;

    int t, row0, mrows;
    if (GROUPED) {
        if (tm >= ctrl[C_NTILES]) return;
        t = ctrl[C_TTASK + tm];
        row0 = ctrl[C_TROW + tm];
        mrows = min(128, ctrl[C_OFFS + t + 1] - row0);
    } else {
        t = 0; row0 = tm * 128; mrows = 128;
    }
    const f16* Wt = W + (long)t * wstride;
    const float* bt = bias + (long)t * bstride;
    int n0 = tn * 128;

    // staging: thread g covers (row g>>3 in a 32-row chunk, LDS slot g&7);
    // global 16B-chunk = (g&7) ^ (row&7)  (inverse swizzle).
    int rowc = tid >> 3;   // 0..31
    long srcElem = (long)rowc * K + (((tid & 7) ^ (rowc & 7)) << 3);
    int dstOff = wave << 10;   // wave-uniform; HW adds lane*16
    const f16* Abase = A + (long)row0 * K + srcElem;
    const f16* Bbase = Wt + (long)n0 * K + srcElem;

    f32x4 acc[4][4];
#pragma unroll
    for (int i = 0; i < 4; ++i)
#pragma unroll
        for (int j = 0; j < 4; ++j) acc[i][j] = (f32x4){0.f, 0.f, 0.f, 0.f};

    // read addressing: byte = row*128 + ((slot)^(lane&7))*16, slot = ks*4+(lane>>4)
    int slot0 = ((lane >> 4) ^ (lane & 7)) << 4;
    const char* aptr = lds + (wm * 64 + (lane & 15)) * 128 + slot0;
    const char* bptr = lds + 16384 + (wn * 64 + (lane & 15)) * 128 + slot0;

    int NI = K >> 6;
    for (int kt = 0; kt < NI; ++kt) {
        // stage K-tile kt into the single buffer
        const f16* a = Abase + kt * 64;
        const f16* b = Bbase + kt * 64;
#pragma unroll
        for (int c = 0; c < 4; ++c) {
            __builtin_amdgcn_global_load_lds(
                (const __attribute__((address_space(1))) unsigned int*)(a + (long)c * 32 * K),
                (__attribute__((address_space(3))) unsigned int*)(lds + c * 4096 + dstOff), 16, 0, 0);
            __builtin_amdgcn_global_load_lds(
                (const __attribute__((address_space(1))) unsigned int*)(b + (long)c * 32 * K),
                (__attribute__((address_space(3))) unsigned int*)(lds + 16384 + c * 4096 + dstOff), 16, 0, 0);
        }
        __syncthreads();   // drains vmcnt/lgkm, buffer ready

#pragma unroll
        for (int ks = 0; ks < 2; ++ks) {
            int so = ks * 64;   // slot XOR 4 <=> byte XOR 64; row part multiple of 128
            f16x8 af[4], bf[4];
#pragma unroll
            for (int mi = 0; mi < 4; ++mi)
                af[mi] = *(const f16x8*)(aptr + mi * 2048 + ((slot0 ^ so) - slot0));
#pragma unroll
            for (int nj = 0; nj < 4; ++nj)
                bf[nj] = *(const f16x8*)(bptr + nj * 2048 + ((slot0 ^ so) - slot0));
#pragma unroll
            for (int mi = 0; mi < 4; ++mi)
#pragma unroll
                for (int nj = 0; nj < 4; ++nj)
                    acc[mi][nj] = __builtin_amdgcn_mfma_f32_16x16x32_f16(af[mi], bf[nj], acc[mi][nj], 0, 0, 0);
        }
        __syncthreads();   // all reads done before next stage overwrites
    }

    // epilogue
    int cq = lane >> 4, cr = lane & 15;
#pragma unroll
    for (int mi = 0; mi < 4; ++mi) {
#pragma unroll
        for (int nj = 0; nj < 4; ++nj) {
#pragma unroll
            for (int reg = 0; reg < 4; ++reg) {
                int rl = wm * 64 + mi * 16 + cq * 4 + reg;
                if (rl >= mrows) continue;
                int gcol = n0 + wn * 64 + nj * 16 + cr;
                if (gcol >= N) continue;
                float v = acc[mi][nj][reg] + bt[gcol];
                int grow = row0 + rl;
                if (EPI == 0) {
                    outF16[(long)grow * H_ + gcol] = (f16)(v > 0.f ? v : 0.f);
                } else if (EPI == 1) {
                    int r = perm[grow];
                    if (gcol < L_) o0[(long)r * L_ + gcol] = v;
                    else o1[(long)r * L_ + (gcol - L_)] = v;
                } else {
                    o0[(long)perm[grow] * D_ + gcol] = 1.f / (1.f + __expf(-v));
                }
            }
        }
    }
}

extern "C" void kernel_launch(void* const* d_in, const int* in_sizes, int n_in,
                              void* d_out, int out_size, void* d_ws, size_t ws_size,
                              hipStream_t stream) {
    const float* x   = (const float*)d_in[0];
    const float* eps = (const float*)d_in[1];
    const float* eW1 = (const float*)d_in[2];
    const float* eb1 = (const float*)d_in[3];
    const float* eW2 = (const float*)d_in[4];
    const float* eb2 = (const float*)d_in[5];
    const float* eW3 = (const float*)d_in[6];
    const float* eb3 = (const float*)d_in[7];
    const float* dW1 = (const float*)d_in[8];
    const float* db1 = (const float*)d_in[9];
    const float* dW2 = (const float*)d_in[10];
    const float* db2 = (const float*)d_in[11];
    const float* hW  = (const float*)d_in[12];
    const float* hb  = (const float*)d_in[13];
    const int* task  = (const int*)d_in[14];

    float* out = (float*)d_out;
    float* recon = out;
    float* mu = out + (size_t)B_ * D_;
    float* ls = mu + (size_t)B_ * L_;

    char* w = (char*)d_ws;
    size_t o = 0;
    auto alloc = [&](size_t bytes) -> char* {
        char* p = w + o;
        o = (o + bytes + 255) & ~(size_t)255;
        return p;
    };
    int* ctrl  = (int*)alloc(4096);
    int* perm  = (int*)alloc((size_t)B_ * 4);
    f16* Xp    = (f16*)alloc((size_t)(B_ + PADROWS) * KP1 * 2);
    f16* H1    = (f16*)alloc((size_t)(B_ + PADROWS) * H_ * 2);
    f16* H2    = (f16*)alloc((size_t)(B_ + PADROWS) * H_ * 2);
    f16* Z     = (f16*)alloc((size_t)(B_ + PADROWS) * L_ * 2);
    f16* Wt1   = (f16*)alloc((size_t)T_ * H_ * KP1 * 2);
    f16* Wt2   = (f16*)alloc((size_t)T_ * H_ * H_ * 2);
    f16* Wt3   = (f16*)alloc((size_t)T_ * 256 * H_ * 2);
    f16* WtD1  = (f16*)alloc((size_t)H_ * L_ * 2);
    f16* WtD2  = (f16*)alloc((size_t)H_ * H_ * 2);
    f16* WtH   = (f16*)alloc((size_t)T_ * NPH * H_ * 2);
    if (o > ws_size) return;

    k_init<<<1, 64, 0, stream>>>(ctrl);
    k_count<<<B_ / 256, 256, 0, stream>>>(task, ctrl);
    k_scan<<<1, 1, 0, stream>>>(ctrl);
    k_scatter<<<B_ / 256, 256, 0, stream>>>(task, ctrl, perm);
    k_gather_x<<<B_, 256, 0, stream>>>(x, perm, Xp);

    k_convW<<<dim3(KP1 / 64, H_ / 64, T_), 256, 0, stream>>>(eW1, Wt1, D_, H_, KP1, H_);
    k_convW<<<dim3(H_ / 64, H_ / 64, T_), 256, 0, stream>>>(eW2, Wt2, H_, H_, H_, H_);
    k_convW<<<dim3(H_ / 64, 256 / 64, T_), 256, 0, stream>>>(eW3, Wt3, H_, 256, H_, 256);
    k_convW<<<dim3(L_ / 64, H_ / 64, 1), 256, 0, stream>>>(dW1, WtD1, L_, H_, L_, H_);
    k_convW<<<dim3(H_ / 64, H_ / 64, 1), 256, 0, stream>>>(dW2, WtD2, H_, H_, H_, H_);
    k_convW<<<dim3(H_ / 64, NPH / 64, T_), 256, 0, stream>>>(hW, WtH, H_, D_, H_, NPH);

    int gridG = MAXTILES * 8;      // 592 (grouped, 8 N-tiles of 128)
    int gridG2 = MAXTILES * 2;     // 148 (enc3, N=256)
    int gridD = (B_ / 128) * 8;    // 512 (dense)
    int gridH = MAXTILES * 7;      // 518 (head, 7 N-tiles cover 784)

    // encoder layer 1: Xp(K=896) @ Wt1 -> relu -> H1
    k_gemmD<0, true><<<gridG, 256, 0, stream>>>(
        Xp, Wt1, (long)H_ * KP1, eb1, H_, KP1, H_, 8, H1, nullptr, nullptr, ctrl, perm);
    // encoder layer 2: H1 @ Wt2 -> relu -> H2
    k_gemmD<0, true><<<gridG, 256, 0, stream>>>(
        H1, Wt2, (long)H_ * H_, eb2, H_, H_, H_, 8, H2, nullptr, nullptr, ctrl, perm);
    // encoder layer 3: H2 @ Wt3 -> mu/ls perm-scatter
    k_gemmD<1, true><<<gridG2, 256, 0, stream>>>(
        H2, Wt3, (long)256 * H_, eb3, 256, H_, 256, 2, nullptr, mu, ls, ctrl, perm);
    // z = mu + exp(ls)*eps
    k_z<<<(B_ * L_) / 256, 256, 0, stream>>>(mu, ls, eps, perm, Z);
    // decoder layer 1: Z(K=128) @ WtD1 -> relu -> H1
    k_gemmD<0, false><<<gridD, 256, 0, stream>>>(
        Z, WtD1, 0, db1, 0, L_, H_, 8, H1, nullptr, nullptr, ctrl, perm);
    // decoder layer 2: H1 @ WtD2 -> relu -> H2
    k_gemmD<0, false><<<gridD, 256, 0, stream>>>(
        H1, WtD2, 0, db2, 0, H_, H_, 8, H2, nullptr, nullptr, ctrl, perm);
    // head: H2 @ WtH -> sigmoid -> recon (perm-scatter fp32)
    k_gemmD<2, true><<<gridH, 256, 0, stream>>>(
        H2, WtH, (long)NPH * H_, hb, D_, H_, D_, 7, nullptr, recon, nullptr, ctrl, perm);
}

// Round 9
// 299.516 us; speedup vs baseline: 1.4247x; 1.1121x over previous
//
#include <hip/hip_runtime.h>

typedef _Float16 f16;
typedef __attribute__((ext_vector_type(4))) _Float16 f16x4;
typedef __attribute__((ext_vector_type(8))) _Float16 f16x8;
typedef __attribute__((ext_vector_type(4))) float f32x4;

#define B_ 8192
#define D_ 784
#define H_ 1024
#define L_ 128
#define T_ 10
#define KP1 896          // D padded to multiple of 64
#define NPH 896          // head N padded to 896 (7 x 128 tiles)
#define MAXTILES (B_/128 + T_)   // 74 (128-row tile map)
#define PADROWS 256

// ctrl int indices
#define C_COUNT 0
#define C_CURS 16
#define C_OFFS 32
#define C_NTILES 49
#define C_TTASK 64
#define C_TROW 160

__global__ void k_init(int* ctrl) {
    if (threadIdx.x < 64) ctrl[threadIdx.x] = 0;
}

__global__ void k_count(const int* __restrict__ task, int* __restrict__ ctrl) {
    int b = blockIdx.x * 256 + threadIdx.x;
    if (b < B_) atomicAdd(&ctrl[C_COUNT + task[b]], 1);
}

__global__ void k_scan(int* ctrl) {
    if (threadIdx.x == 0 && blockIdx.x == 0) {
        int off = 0;
        ctrl[C_OFFS] = 0;
        for (int t = 0; t < T_; ++t) { off += ctrl[C_COUNT + t]; ctrl[C_OFFS + t + 1] = off; }
        int nt = 0;
        for (int t = 0; t < T_; ++t)
            for (int r = ctrl[C_OFFS + t]; r < ctrl[C_OFFS + t + 1]; r += 128) {
                ctrl[C_TTASK + nt] = t; ctrl[C_TROW + nt] = r; ++nt;
            }
        ctrl[C_NTILES] = nt;
    }
}

__global__ void k_scatter(const int* __restrict__ task, int* __restrict__ ctrl, int* __restrict__ perm) {
    int b = blockIdx.x * 256 + threadIdx.x;
    if (b >= B_) return;
    int t = task[b];
    int i = ctrl[C_OFFS + t] + atomicAdd(&ctrl[C_CURS + t], 1);
    perm[i] = b;
}

__global__ void k_gather_x(const float* __restrict__ x, const int* __restrict__ perm, f16* __restrict__ Xp) {
    int i = blockIdx.x;
    int r = perm[i];
    int c = threadIdx.x * 4;
    if (c >= KP1) return;
    f16x4 o = (f16x4){0, 0, 0, 0};
    if (c < D_) {
        float4 v = *(const float4*)(x + (long)r * D_ + c);
        o[0] = (f16)v.x; o[1] = (f16)v.y; o[2] = (f16)v.z; o[3] = (f16)v.w;
    }
    *(f16x4*)(Xp + (long)i * KP1 + c) = o;
}

// ---------------------------------------------------------------------------
// Fused transpose-convert for ALL weight tensors in one launch.
// src fp32 [T][K][N] -> dst f16 [T][Np][Kp], zero-padded. 64x64 tiles.
// Reads: wave = 4 full rows of 256B (fully coalesced float4).
// ---------------------------------------------------------------------------
struct ConvSeg { const float* src; f16* dst; int K, N, Kp, Np, ntx, nty, base; };
struct ConvArgs { ConvSeg s[6]; };

__global__ void k_convAll(ConvArgs args) {
    __shared__ float tile[64][65];
    int bid = blockIdx.x;
    // find segment
    int si = 0;
#pragma unroll
    for (int i = 1; i < 6; ++i) si = (bid >= args.s[i].base) ? i : si;
    ConvSeg sg = args.s[si];
    int rel = bid - sg.base;
    int perT = sg.ntx * sg.nty;
    int t = rel / perT; rel -= t * perT;
    int ty = rel / sg.ntx;            // Np tile
    int tx = rel - ty * sg.ntx;       // Kp tile
    int k0 = tx * 64, n0 = ty * 64;
    const float* s = sg.src + (long)t * sg.K * sg.N;
    f16* d = sg.dst + (long)t * sg.Np * sg.Kp;
    int tid = threadIdx.x;

    // read: 16 threads per row (float4 each), 16 rows per pass, 4 passes
    int rr = tid >> 4, cc = (tid & 15) * 4;
#pragma unroll
    for (int p = 0; p < 4; ++p) {
        int k = k0 + rr + p * 16;
        int gn = n0 + cc;
        float4 v = {0.f, 0.f, 0.f, 0.f};
        if (k < sg.K) {
            const float* sp = s + (long)k * sg.N + gn;
            if (gn + 3 < sg.N) v = *(const float4*)sp;
            else {
                if (gn + 0 < sg.N) v.x = sp[0];
                if (gn + 1 < sg.N) v.y = sp[1];
                if (gn + 2 < sg.N) v.z = sp[2];
                if (gn + 3 < sg.N) v.w = sp[3];
            }
        }
        tile[rr + p * 16][cc + 0] = v.x;
        tile[rr + p * 16][cc + 1] = v.y;
        tile[rr + p * 16][cc + 2] = v.z;
        tile[rr + p * 16][cc + 3] = v.w;
    }
    __syncthreads();
    // write: 8 threads per output row (f16x8 each), 32 rows per pass, 2 passes
    int nr = tid >> 3, kk = (tid & 7) * 8;
#pragma unroll
    for (int p = 0; p < 2; ++p) {
        int n = n0 + nr + p * 32;
        f16x8 o;
#pragma unroll
        for (int u = 0; u < 8; ++u) o[u] = (f16)tile[kk + u][nr + p * 32];
        if (n < sg.Np) *(f16x8*)(d + (long)n * sg.Kp + k0 + kk) = o;
    }
}

// z = mu + exp(ls) * eps  (permuted rows)
__global__ void k_z(const float* __restrict__ mu, const float* __restrict__ ls,
                    const float* __restrict__ eps, const int* __restrict__ perm,
                    f16* __restrict__ Z) {
    long gid = (long)blockIdx.x * 256 + threadIdx.x;
    int i = (int)(gid >> 7), c = (int)(gid & 127);
    int r = perm[i];
    float m = mu[(long)r * L_ + c];
    float l = ls[(long)r * L_ + c];
    Z[(long)i * L_ + c] = (f16)(m + __expf(l) * eps[(long)r * L_ + c]);
}

// ---------------------------------------------------------------------------
// m97-faithful 128x128 GEMM, BK=64, SINGLE 32KB LDS buffer, 4 waves (2Mx2N),
// per-wave 64x64 = acc[4][4] of 16x16x32 f16 MFMA. launch_bounds(256,4):
// 64 VGPR + 64 AGPR = 128 regs -> 4 blocks/CU co-resident (latency hiding
// comes from inter-block overlap, m114; intra-block pipelining is null, m99).
// ---------------------------------------------------------------------------
template <int EPI, bool GROUPED>
__global__ __launch_bounds__(256, 4)
void k_gemmD(const f16* __restrict__ A,
             const f16* __restrict__ W, long wstride,
             const float* __restrict__ bias, int bstride,
             int K, int N, int ntn,
             f16* __restrict__ outF16, float* __restrict__ o0, float* __restrict__ o1,
             const int* __restrict__ ctrl, const int* __restrict__ perm) {
    __shared__ char lds[32768];   // A [128][64]f16 @0 (16KB), B @16384 (16KB)
    int tid = threadIdx.x, lane = tid & 63;
    int wave = tid >> 6, wm = wave >> 1, wn = wave & 1;

    // bijective XCD swizzle (m204)
    int nwg = gridDim.x, orig = blockIdx.x;
    int qq = nwg >> 3, rr8 = nwg & 7, xcd = orig & 7, idx = orig >> 3;
    int wgid = (xcd < rr8 ? xcd * (qq + 1) : rr8 * (qq + 1) + (xcd - rr8) * qq) + idx;
    int tm = wgid / ntn, tn = wgid - tm * ntn;

    int t, row0, mrows;
    if (GROUPED) {
        if (tm >= ctrl[C_NTILES]) return;
        t = ctrl[C_TTASK + tm];
        row0 = ctrl[C_TROW + tm];
        mrows = min(128, ctrl[C_OFFS + t + 1] - row0);
    } else {
        t = 0; row0 = tm * 128; mrows = 128;
    }
    const f16* Wt = W + (long)t * wstride;
    const float* bt = bias + (long)t * bstride;
    int n0 = tn * 128;

    // staging: thread g covers (row g>>3 in a 32-row chunk, LDS slot g&7);
    // global 16B-chunk = (g&7) ^ (row&7)  (inverse swizzle).
    int rowc = tid >> 3;   // 0..31
    long srcElem = (long)rowc * K + (((tid & 7) ^ (rowc & 7)) << 3);
    int dstOff = wave << 10;   // wave-uniform; HW adds lane*16
    const f16* Abase = A + (long)row0 * K + srcElem;
    const f16* Bbase = Wt + (long)n0 * K + srcElem;

    f32x4 acc[4][4];
#pragma unroll
    for (int i = 0; i < 4; ++i)
#pragma unroll
        for (int j = 0; j < 4; ++j) acc[i][j] = (f32x4){0.f, 0.f, 0.f, 0.f};

    // read addressing: byte = row*128 + ((slot)^(lane&7))*16, slot = ks*4+(lane>>4)
    int slot0 = ((lane >> 4) ^ (lane & 7)) << 4;
    const char* aptr = lds + (wm * 64 + (lane & 15)) * 128 + slot0;
    const char* bptr = lds + 16384 + (wn * 64 + (lane & 15)) * 128 + slot0;

    int NI = K >> 6;
    for (int kt = 0; kt < NI; ++kt) {
        const f16* a = Abase + kt * 64;
        const f16* b = Bbase + kt * 64;
#pragma unroll
        for (int c = 0; c < 4; ++c) {
            __builtin_amdgcn_global_load_lds(
                (const __attribute__((address_space(1))) unsigned int*)(a + (long)c * 32 * K),
                (__attribute__((address_space(3))) unsigned int*)(lds + c * 4096 + dstOff), 16, 0, 0);
            __builtin_amdgcn_global_load_lds(
                (const __attribute__((address_space(1))) unsigned int*)(b + (long)c * 32 * K),
                (__attribute__((address_space(3))) unsigned int*)(lds + 16384 + c * 4096 + dstOff), 16, 0, 0);
        }
        __syncthreads();   // drains vmcnt/lgkm, buffer ready

#pragma unroll
        for (int ks = 0; ks < 2; ++ks) {
            int so = ks * 64;   // slot XOR 4 <=> byte XOR 64
            f16x8 af[4], bf[4];
#pragma unroll
            for (int mi = 0; mi < 4; ++mi)
                af[mi] = *(const f16x8*)(aptr + mi * 2048 + ((slot0 ^ so) - slot0));
#pragma unroll
            for (int nj = 0; nj < 4; ++nj)
                bf[nj] = *(const f16x8*)(bptr + nj * 2048 + ((slot0 ^ so) - slot0));
#pragma unroll
            for (int mi = 0; mi < 4; ++mi)
#pragma unroll
                for (int nj = 0; nj < 4; ++nj)
                    acc[mi][nj] = __builtin_amdgcn_mfma_f32_16x16x32_f16(af[mi], bf[nj], acc[mi][nj], 0, 0, 0);
        }
        __syncthreads();   // all reads done before next stage overwrites
    }

    // epilogue
    int cq = lane >> 4, cr = lane & 15;
#pragma unroll
    for (int mi = 0; mi < 4; ++mi) {
#pragma unroll
        for (int nj = 0; nj < 4; ++nj) {
#pragma unroll
            for (int reg = 0; reg < 4; ++reg) {
                int rl = wm * 64 + mi * 16 + cq * 4 + reg;
                if (rl >= mrows) continue;
                int gcol = n0 + wn * 64 + nj * 16 + cr;
                if (gcol >= N) continue;
                float v = acc[mi][nj][reg] + bt[gcol];
                int grow = row0 + rl;
                if (EPI == 0) {
                    outF16[(long)grow * H_ + gcol] = (f16)(v > 0.f ? v : 0.f);
                } else if (EPI == 1) {
                    int r = perm[grow];
                    if (gcol < L_) o0[(long)r * L_ + gcol] = v;
                    else o1[(long)r * L_ + (gcol - L_)] = v;
                } else {
                    o0[(long)perm[grow] * D_ + gcol] = 1.f / (1.f + __expf(-v));
                }
            }
        }
    }
}

extern "C" void kernel_launch(void* const* d_in, const int* in_sizes, int n_in,
                              void* d_out, int out_size, void* d_ws, size_t ws_size,
                              hipStream_t stream) {
    const float* x   = (const float*)d_in[0];
    const float* eps = (const float*)d_in[1];
    const float* eW1 = (const float*)d_in[2];
    const float* eb1 = (const float*)d_in[3];
    const float* eW2 = (const float*)d_in[4];
    const float* eb2 = (const float*)d_in[5];
    const float* eW3 = (const float*)d_in[6];
    const float* eb3 = (const float*)d_in[7];
    const float* dW1 = (const float*)d_in[8];
    const float* db1 = (const float*)d_in[9];
    const float* dW2 = (const float*)d_in[10];
    const float* db2 = (const float*)d_in[11];
    const float* hW  = (const float*)d_in[12];
    const float* hb  = (const float*)d_in[13];
    const int* task  = (const int*)d_in[14];

    float* out = (float*)d_out;
    float* recon = out;
    float* mu = out + (size_t)B_ * D_;
    float* ls = mu + (size_t)B_ * L_;

    char* w = (char*)d_ws;
    size_t o = 0;
    auto alloc = [&](size_t bytes) -> char* {
        char* p = w + o;
        o = (o + bytes + 255) & ~(size_t)255;
        return p;
    };
    int* ctrl  = (int*)alloc(4096);
    int* perm  = (int*)alloc((size_t)B_ * 4);
    f16* Xp    = (f16*)alloc((size_t)(B_ + PADROWS) * KP1 * 2);
    f16* H1    = (f16*)alloc((size_t)(B_ + PADROWS) * H_ * 2);
    f16* H2    = (f16*)alloc((size_t)(B_ + PADROWS) * H_ * 2);
    f16* Z     = (f16*)alloc((size_t)(B_ + PADROWS) * L_ * 2);
    f16* Wt1   = (f16*)alloc((size_t)T_ * H_ * KP1 * 2);
    f16* Wt2   = (f16*)alloc((size_t)T_ * H_ * H_ * 2);
    f16* Wt3   = (f16*)alloc((size_t)T_ * 256 * H_ * 2);
    f16* WtD1  = (f16*)alloc((size_t)H_ * L_ * 2);
    f16* WtD2  = (f16*)alloc((size_t)H_ * H_ * 2);
    f16* WtH   = (f16*)alloc((size_t)T_ * NPH * H_ * 2);
    if (o > ws_size) return;

    k_init<<<1, 64, 0, stream>>>(ctrl);
    k_count<<<B_ / 256, 256, 0, stream>>>(task, ctrl);
    k_scan<<<1, 1, 0, stream>>>(ctrl);
    k_scatter<<<B_ / 256, 256, 0, stream>>>(task, ctrl, perm);
    k_gather_x<<<B_, 256, 0, stream>>>(x, perm, Xp);

    // fused weight transpose-convert (one launch)
    ConvArgs ca;
    int base = 0;
    auto seg = [&](const float* s, f16* d, int K, int N, int Kp, int Np, int T) {
        ConvSeg sg; sg.src = s; sg.dst = d; sg.K = K; sg.N = N; sg.Kp = Kp; sg.Np = Np;
        sg.ntx = Kp / 64; sg.nty = Np / 64; sg.base = base;
        base += sg.ntx * sg.nty * T;
        return sg;
    };
    ca.s[0] = seg(eW1, Wt1, D_, H_, KP1, H_, T_);
    ca.s[1] = seg(eW2, Wt2, H_, H_, H_, H_, T_);
    ca.s[2] = seg(eW3, Wt3, H_, 256, H_, 256, T_);
    ca.s[3] = seg(dW1, WtD1, L_, H_, L_, H_, 1);
    ca.s[4] = seg(dW2, WtD2, H_, H_, H_, H_, 1);
    ca.s[5] = seg(hW, WtH, H_, D_, H_, NPH, T_);
    k_convAll<<<base, 256, 0, stream>>>(ca);

    int gridG = MAXTILES * 8;      // 592 (grouped, 8 N-tiles of 128)
    int gridG2 = MAXTILES * 2;     // 148 (enc3, N=256)
    int gridD = (B_ / 128) * 8;    // 512 (dense)
    int gridH = MAXTILES * 7;      // 518 (head, 7 N-tiles cover 784)

    // encoder layer 1: Xp(K=896) @ Wt1 -> relu -> H1
    k_gemmD<0, true><<<gridG, 256, 0, stream>>>(
        Xp, Wt1, (long)H_ * KP1, eb1, H_, KP1, H_, 8, H1, nullptr, nullptr, ctrl, perm);
    // encoder layer 2: H1 @ Wt2 -> relu -> H2
    k_gemmD<0, true><<<gridG, 256, 0, stream>>>(
        H1, Wt2, (long)H_ * H_, eb2, H_, H_, H_, 8, H2, nullptr, nullptr, ctrl, perm);
    // encoder layer 3: H2 @ Wt3 -> mu/ls perm-scatter
    k_gemmD<1, true><<<gridG2, 256, 0, stream>>>(
        H2, Wt3, (long)256 * H_, eb3, 256, H_, 256, 2, nullptr, mu, ls, ctrl, perm);
    // z = mu + exp(ls)*eps
    k_z<<<(B_ * L_) / 256, 256, 0, stream>>>(mu, ls, eps, perm, Z);
    // decoder layer 1: Z(K=128) @ WtD1 -> relu -> H1
    k_gemmD<0, false><<<gridD, 256, 0, stream>>>(
        Z, WtD1, 0, db1, 0, L_, H_, 8, H1, nullptr, nullptr, ctrl, perm);
    // decoder layer 2: H1 @ WtD2 -> relu -> H2
    k_gemmD<0, false><<<gridD, 256, 0, stream>>>(
        H1, WtD2, 0, db2, 0, H_, H_, 8, H2, nullptr, nullptr, ctrl, perm);
    // head: H2 @ WtH -> sigmoid -> recon (perm-scatter fp32)
    k_gemmD<2, true><<<gridH, 256, 0, stream>>>(
        H2, WtH, (long)NPH * H_, hb, D_, H_, D_, 7, nullptr, recon, nullptr, ctrl, perm);
}